// Round 15
// baseline (246.137 us; speedup 1.0000x reference)
//
#include <hip/hip_runtime.h>

#define NUM_USERS  150000
#define NUM_ITEMS  140000
#define NUM_BRANDS 10000
#define N_NODES    300000
#define DIM        64
#define N_EDGES    1200000
#define OUT_ROWS   290000          // users + items

#define CHUNK      1024            // elements per scan block
#define NB         ((N_NODES + CHUNK - 1) / CHUNK)   // 293 scan blocks

#define NBIN       8               // one bin per XCD
#define BINSZ      (N_EDGES / NBIN)                  // 150000 csr records/bin

// ---------------------------------------------------------------------------
// bf16 helpers (h1/h2 stored as packed bf16: 64 dims = 8 uint4 per row)
// ---------------------------------------------------------------------------
__device__ __forceinline__ float bf_lo(unsigned u) { return __uint_as_float(u << 16); }
__device__ __forceinline__ float bf_hi(unsigned u) { return __uint_as_float(u & 0xffff0000u); }
__device__ __forceinline__ unsigned pack_bf(float a, float b) {
    unsigned ua = __float_as_uint(a); ua += 0x7fffu + ((ua >> 16) & 1u);
    unsigned ub = __float_as_uint(b); ub += 0x7fffu + ((ub >> 16) & 1u);
    return (ua >> 16) | (ub & 0xffff0000u);
}

// ---------------------------------------------------------------------------
// histogram of destination degrees + per-edge rank within its row
// ---------------------------------------------------------------------------
__global__ void lgcn_hist(const int* __restrict__ dst,
                          int* __restrict__ counts,
                          int* __restrict__ rank) {
    int e = blockIdx.x * blockDim.x + threadIdx.x;
    if (e >= N_EDGES) return;
    rank[e] = atomicAdd(&counts[dst[e]], 1);
}

// ---------------------------------------------------------------------------
// scan phase 1: per-1024-chunk exclusive scan (256 thr x 4 elem), chunk sums
// ---------------------------------------------------------------------------
__global__ void lgcn_scan_p1(const int* __restrict__ counts,
                             int* __restrict__ rowptr,
                             int* __restrict__ blockSums) {
    __shared__ int ts[256];
    int b    = blockIdx.x;
    int base = b * CHUNK;
    int t    = threadIdx.x;
    int c[4];
    int s = 0;
#pragma unroll
    for (int i = 0; i < 4; ++i) {
        int g = base + t * 4 + i;
        c[i] = (g < N_NODES) ? counts[g] : 0;
        s += c[i];
    }
    ts[t] = s;
    __syncthreads();
    for (int off = 1; off < 256; off <<= 1) {
        int v = (t >= off) ? ts[t - off] : 0;
        __syncthreads();
        ts[t] += v;
        __syncthreads();
    }
    int run = ts[t] - s;     // exclusive prefix of this thread's 4-group
#pragma unroll
    for (int i = 0; i < 4; ++i) {
        int g = base + t * 4 + i;
        if (g < N_NODES) rowptr[g] = run;
        run += c[i];
    }
    if (t == 255) blockSums[b] = ts[255];
}

// ---------------------------------------------------------------------------
// scan phase 2: single block exclusive-scans the NB (=293) chunk sums
// ---------------------------------------------------------------------------
__global__ void lgcn_scan_p2(int* __restrict__ blockSums) {
    __shared__ int sh[512];
    int t = threadIdx.x;
    int v = (t < NB) ? blockSums[t] : 0;
    sh[t] = v;
    __syncthreads();
    for (int off = 1; off < 512; off <<= 1) {
        int u = (t >= off) ? sh[t - off] : 0;
        __syncthreads();
        sh[t] += u;
        __syncthreads();
    }
    if (t < NB) blockSums[t] = sh[t] - v;   // exclusive
}

// ---------------------------------------------------------------------------
// scan phase 3: add chunk offsets; rowptr[N_NODES] = N_EDGES
// ---------------------------------------------------------------------------
__global__ void lgcn_scan_p3(int* __restrict__ rowptr,
                             const int* __restrict__ blockSums) {
    int b    = blockIdx.x;
    int base = b * CHUNK;
    int t    = threadIdx.x;
    int off  = blockSums[b];
#pragma unroll
    for (int i = 0; i < 4; ++i) {
        int g = base + t * 4 + i;
        if (g < N_NODES) rowptr[g] += off;
    }
    if (b == 0 && t == 0) rowptr[N_NODES] = N_EDGES;
}

// ---------------------------------------------------------------------------
// pos precompute: one pass so the 8 binned passes re-read only pos (4.8MB)
// (R11/R13 evidence: cuts csr_bin to ~14us vs ~65 fused)
// ---------------------------------------------------------------------------
__global__ void lgcn_pos(const int* __restrict__ dst,
                         const int* __restrict__ rank,
                         const int* __restrict__ rowptr,
                         int* __restrict__ pos) {
    int e = blockIdx.x * blockDim.x + threadIdx.x;
    if (e >= N_EDGES) return;
    pos[e] = rowptr[dst[e]] + rank[e];
}

// ---------------------------------------------------------------------------
// XCD-private binned CSR build: block b handles edge chunk (b>>3), position
// bin (b&7). blockIdx%8 -> XCD, so each bin's csr lines are dirtied by one
// XCD's L2 and mostly evict full.
// ---------------------------------------------------------------------------
__global__ void lgcn_csr_bin(const int*   __restrict__ src,
                             const float* __restrict__ vals,
                             const int*   __restrict__ pos,
                             uint2*       __restrict__ csr) {
    int b    = blockIdx.x;
    int bin  = b & (NBIN - 1);
    int e    = (b >> 3) * blockDim.x + threadIdx.x;
    if (e >= N_EDGES) return;
    int p  = pos[e];
    int lo = bin * BINSZ;
    if (p >= lo && p < lo + BINSZ) {
        csr[p] = make_uint2((unsigned)src[e], __float_as_uint(vals[e]));
    }
}

// ---------------------------------------------------------------------------
// fp32 ego row lookup: concat(user,item,brand) without materializing it
// ---------------------------------------------------------------------------
__device__ __forceinline__ const float4* ego_row(const float* __restrict__ user,
                                                 const float* __restrict__ item,
                                                 const float* __restrict__ brand,
                                                 int r) {
    if (r < NUM_USERS)
        return reinterpret_cast<const float4*>(user) + (r << 4);
    else if (r < NUM_USERS + NUM_ITEMS)
        return reinterpret_cast<const float4*>(item) + ((r - NUM_USERS) << 4);
    else
        return reinterpret_cast<const float4*>(brand) + ((r - NUM_USERS - NUM_ITEMS) << 4);
}

// ---------------------------------------------------------------------------
// LAYER 1 gather (separate non-template function so its fp32 codegen can't
// perturb the bf16 gathers' regalloc): 8 lanes/node, 2-deep pipeline reading
// fp32 ego rows directly (R7-measured ~62us). Writes h1 (bf16).
// ---------------------------------------------------------------------------
__global__ void __launch_bounds__(256, 8)
lgcn_gather1(const int*   __restrict__ rowptr,
             const uint2* __restrict__ csr,
             const float* __restrict__ user,
             const float* __restrict__ item,
             const float* __restrict__ brand,
             uint4*       __restrict__ h_out) {
    int g    = blockIdx.x * blockDim.x + threadIdx.x;   // node*8 + q
    int node = g >> 3;
    int q    = g & 7;
    int beg = rowptr[node];
    int end = rowptr[node + 1];
    float4 s0 = make_float4(0.f, 0.f, 0.f, 0.f);
    float4 s1 = make_float4(0.f, 0.f, 0.f, 0.f);
    if (beg < end) {
        uint2 rec0 = csr[beg];
        uint2 rec1 = csr[(beg + 1 < end) ? beg + 1 : beg];
        const float4* p0 = ego_row(user, item, brand, (int)rec0.x);
        float4 a0 = p0[2 * q];
        float4 b0 = p0[2 * q + 1];
        for (int j = beg; j < end; ++j) {
            int jn = j + 2 < end ? j + 2 : end - 1;
            uint2 rec2 = csr[jn];                       // rec, 2 ahead
            const float4* p1 = ego_row(user, item, brand, (int)rec1.x);
            float4 a1 = p1[2 * q];
            float4 b1 = p1[2 * q + 1];
            float v = __uint_as_float(rec0.y);
            s0.x = fmaf(a0.x, v, s0.x);
            s0.y = fmaf(a0.y, v, s0.y);
            s0.z = fmaf(a0.z, v, s0.z);
            s0.w = fmaf(a0.w, v, s0.w);
            s1.x = fmaf(b0.x, v, s1.x);
            s1.y = fmaf(b0.y, v, s1.y);
            s1.z = fmaf(b0.z, v, s1.z);
            s1.w = fmaf(b0.w, v, s1.w);
            rec0 = rec1; rec1 = rec2; a0 = a1; b0 = b1;
        }
    }
    uint4 w;
    w.x = pack_bf(s0.x, s0.y);
    w.y = pack_bf(s0.z, s0.w);
    w.z = pack_bf(s1.x, s1.y);
    w.w = pack_bf(s1.z, s1.w);
    h_out[g] = w;
}

// ---------------------------------------------------------------------------
// bf16 gather core (R12's exact 4-deep raw-word loop, measured ~55us):
// recs prefetched 4 ahead, rows staged 3 deep as raw uint4, unpack at fma.
// ---------------------------------------------------------------------------
__device__ __forceinline__ void gather_bf_core(int beg, int end, int q,
                                               const uint2* __restrict__ csr,
                                               const uint4* __restrict__ h_src,
                                               float4& s0, float4& s1) {
    int last = end - 1;
    uint2 rec0 = csr[beg];
    uint2 rec1 = csr[beg + 1 < end ? beg + 1 : last];
    uint2 rec2 = csr[beg + 2 < end ? beg + 2 : last];
    uint2 rec3 = csr[beg + 3 < end ? beg + 3 : last];
    uint4 w0 = h_src[((int)rec0.x << 3) + q];
    uint4 w1 = h_src[((int)rec1.x << 3) + q];
    uint4 w2 = h_src[((int)rec2.x << 3) + q];
    for (int j = beg; j < end; ++j) {
        int jn = j + 4 < end ? j + 4 : last;
        uint2 rec4 = csr[jn];                           // rec, 4 ahead
        uint4 w3 = h_src[((int)rec3.x << 3) + q];       // row, 3 ahead (raw)
        float v = __uint_as_float(rec0.y);
        s0.x = fmaf(bf_lo(w0.x), v, s0.x);
        s0.y = fmaf(bf_hi(w0.x), v, s0.y);
        s0.z = fmaf(bf_lo(w0.y), v, s0.z);
        s0.w = fmaf(bf_hi(w0.y), v, s0.w);
        s1.x = fmaf(bf_lo(w0.z), v, s1.x);
        s1.y = fmaf(bf_hi(w0.z), v, s1.y);
        s1.z = fmaf(bf_lo(w0.w), v, s1.z);
        s1.w = fmaf(bf_hi(w0.w), v, s1.w);
        rec0 = rec1; rec1 = rec2; rec2 = rec3; rec3 = rec4;
        w0 = w1; w1 = w2; w2 = w3;
    }
}

// ---------------------------------------------------------------------------
// LAYER 2 gather: h1(bf16) -> h2(bf16)
// ---------------------------------------------------------------------------
__global__ void __launch_bounds__(256, 8)
lgcn_gather2(const int*   __restrict__ rowptr,
             const uint2* __restrict__ csr,
             const uint4* __restrict__ h_src,
             uint4*       __restrict__ h_out) {
    int g    = blockIdx.x * blockDim.x + threadIdx.x;   // node*8 + q
    int node = g >> 3;
    int q    = g & 7;
    int beg = rowptr[node];
    int end = rowptr[node + 1];
    float4 s0 = make_float4(0.f, 0.f, 0.f, 0.f);
    float4 s1 = make_float4(0.f, 0.f, 0.f, 0.f);
    if (beg < end) gather_bf_core(beg, end, q, csr, h_src, s0, s1);
    uint4 w;
    w.x = pack_bf(s0.x, s0.y);
    w.y = pack_bf(s0.z, s0.w);
    w.z = pack_bf(s1.x, s1.y);
    w.w = pack_bf(s1.z, s1.w);
    h_out[g] = w;
}

// ---------------------------------------------------------------------------
// LAYER 3 gather: h2(bf16) -> fused out = (ego + h1 + h2 + sum) * 0.25
// ---------------------------------------------------------------------------
__global__ void __launch_bounds__(256, 8)
lgcn_gather3(const int*   __restrict__ rowptr,
             const uint2* __restrict__ csr,
             const uint4* __restrict__ h_src,
             const float* __restrict__ user,
             const float* __restrict__ item,
             const float* __restrict__ brand,
             const uint4* __restrict__ h1,
             float*       __restrict__ out) {
    int g    = blockIdx.x * blockDim.x + threadIdx.x;   // node*8 + q
    int node = g >> 3;
    int q    = g & 7;
    int beg = rowptr[node];
    int end = rowptr[node + 1];
    float4 s0 = make_float4(0.f, 0.f, 0.f, 0.f);
    float4 s1 = make_float4(0.f, 0.f, 0.f, 0.f);
    if (beg < end) gather_bf_core(beg, end, q, csr, h_src, s0, s1);
    if (node < OUT_ROWS) {
        const float4* er = ego_row(user, item, brand, node);
        float4 e0 = er[2 * q];
        float4 e1 = er[2 * q + 1];
        uint4 w1 = h1[g];
        uint4 w2 = h_src[g];                            // h2 own row
        float4 o0, o1;
        o0.x = (e0.x + bf_lo(w1.x) + bf_lo(w2.x) + s0.x) * 0.25f;
        o0.y = (e0.y + bf_hi(w1.x) + bf_hi(w2.x) + s0.y) * 0.25f;
        o0.z = (e0.z + bf_lo(w1.y) + bf_lo(w2.y) + s0.z) * 0.25f;
        o0.w = (e0.w + bf_hi(w1.y) + bf_hi(w2.y) + s0.w) * 0.25f;
        o1.x = (e1.x + bf_lo(w1.z) + bf_lo(w2.z) + s1.x) * 0.25f;
        o1.y = (e1.y + bf_hi(w1.z) + bf_hi(w2.z) + s1.y) * 0.25f;
        o1.z = (e1.z + bf_lo(w1.w) + bf_lo(w2.w) + s1.z) * 0.25f;
        o1.w = (e1.w + bf_hi(w1.w) + bf_hi(w2.w) + s1.w) * 0.25f;
        float4* o = reinterpret_cast<float4*>(out) + g * 2;
        o[0] = o0;
        o[1] = o1;
    }
}

extern "C" void kernel_launch(void* const* d_in, const int* in_sizes, int n_in,
                              void* d_out, int out_size, void* d_ws, size_t ws_size,
                              hipStream_t stream) {
    const float* user  = (const float*)d_in[0];
    const float* item  = (const float*)d_in[1];
    const float* brand = (const float*)d_in[2];
    const float* vals  = (const float*)d_in[3];
    const int*   src   = (const int*)d_in[4];
    const int*   dst   = (const int*)d_in[5];
    float* out = (float*)d_out;

    // workspace layout (32-bit words); 16B alignment holds for uint4 arrays
    size_t W = 0;
    uint4* h1  = (uint4*)d_ws;                 W += (size_t)N_NODES * 32;   // bf16 rows (128B)
    uint4* h2  = (uint4*)((int*)d_ws + W);     W += (size_t)N_NODES * 32;
    uint2* csr = (uint2*)((int*)d_ws + W);     W += (size_t)N_EDGES * 2;
    int* rank      = (int*)d_ws + W;           W += N_EDGES;
    int* pos       = (int*)d_ws + W;           W += N_EDGES;
    int* rowptr    = (int*)d_ws + W;           W += N_NODES + 2;
    int* counts    = (int*)d_ws + W;           W += N_NODES;       // memset
    int* blockSums = (int*)d_ws + W;           W += 512;
    (void)ws_size; (void)n_in; (void)in_sizes; (void)out_size;

    const int edgeBlocks   = (N_EDGES + 255) / 256;     // 4688
    const int gatherBlocks = (N_NODES * 8) / 256;       // 9375 (8 thr/node)

    // zero degree counters (workspace is poisoned; hist accumulates)
    hipMemsetAsync(counts, 0, (size_t)N_NODES * sizeof(int), stream);

    // build dst-sorted CSR: hist+rank -> scan -> pos -> XCD-binned scatter
    lgcn_hist   <<<edgeBlocks, 256, 0, stream>>>(dst, counts, rank);
    lgcn_scan_p1<<<NB, 256, 0, stream>>>(counts, rowptr, blockSums);
    lgcn_scan_p2<<<1, 512, 0, stream>>>(blockSums);
    lgcn_scan_p3<<<NB, 256, 0, stream>>>(rowptr, blockSums);
    lgcn_pos    <<<edgeBlocks, 256, 0, stream>>>(dst, rank, rowptr, pos);
    lgcn_csr_bin<<<NBIN * edgeBlocks, 256, 0, stream>>>(src, vals, pos, csr);

    // 3 atomic-free SpMM layers (bf16 intermediates); residual fused in L3
    lgcn_gather1<<<gatherBlocks, 256, 0, stream>>>(rowptr, csr, user, item, brand, h1);
    lgcn_gather2<<<gatherBlocks, 256, 0, stream>>>(rowptr, csr, h1, h2);
    lgcn_gather3<<<gatherBlocks, 256, 0, stream>>>(rowptr, csr, h2, user, item, brand,
                                                   h1, out);
}